// Round 17
// baseline (392.844 us; speedup 1.0000x reference)
//
#include <hip/hip_runtime.h>

#define N_NODES 239616
#define NLM 468
#define BSZ 512
#define NEDGE 3833856
#define IN_C 64
#define OUT_C 128
#define KW 3
#define EPSV 1e-5f

#define GM 128      // nodes per gemm1/final block (MFMA tile M)
#define LCH 128     // L-rows per conv block
#define NCHK 4
#define NBUCK 117   // dst>>11 buckets (2048 nodes each; 117*2048 == N exactly)
#define BCH 4096    // edges per k_bucket block (E = 4096*936 exactly)
#define BCAP 36864  // fixed bucket capacity (mean 32768 + 22 sigma)
#define NSUM 8      // replicated stats buffers

typedef __attribute__((ext_vector_type(8))) __bf16 bf16x8;
typedef __attribute__((ext_vector_type(4))) float f32x4;

__device__ inline unsigned short f2bf(float f) {
    unsigned int u = __builtin_bit_cast(unsigned int, f);
    u = (u + 0x7FFFu + ((u >> 16) & 1u)) >> 16;
    return (unsigned short)u;
}
__device__ inline float bf2f(unsigned short b) {
    return __builtin_bit_cast(float, (unsigned)b << 16);
}

// ================= CSR build (bucketed counting sort by dst) =================

__global__ void k_binit(int* __restrict__ gbcnt) {
    int b = threadIdx.x;
    if (b < NBUCK) gbcnt[b] = b * BCAP;
}

// Pass A: block-local radix scatter; bp holds u32-packed (local_dst<<18 | src)
__global__ __launch_bounds__(256) void k_bucket(const int* __restrict__ ei,
                                                int* __restrict__ gbcnt,
                                                unsigned* __restrict__ bp) {
    __shared__ int h[128], sc[128], cur2[128], base[128];
    __shared__ unsigned long long pairs[BCH];   // 32 KB
    const int t = threadIdx.x;
    const int e0 = blockIdx.x * BCH;

    if (t < 128) h[t] = 0;
    __syncthreads();

    int d[16], s[16];
    #pragma unroll
    for (int i = 0; i < 16; ++i) {
        int e = e0 + i * 256 + t;
        d[i] = ei[NEDGE + e];
        s[i] = ei[e];
    }
    #pragma unroll
    for (int i = 0; i < 16; ++i) atomicAdd(&h[d[i] >> 11], 1);
    __syncthreads();

    if (t < 128) sc[t] = h[t];
    __syncthreads();
    for (int dd = 1; dd < 128; dd <<= 1) {
        int v = 0;
        if (t < 128 && t >= dd) v = sc[t - dd];
        __syncthreads();
        if (t < 128) sc[t] += v;
        __syncthreads();
    }
    if (t < 128) {
        int excl = sc[t] - h[t];
        cur2[t] = excl;
        base[t] = (h[t] > 0) ? atomicAdd(&gbcnt[t], h[t]) : 0;
    }
    __syncthreads();

    #pragma unroll
    for (int i = 0; i < 16; ++i) {
        int b = d[i] >> 11;
        int p = atomicAdd(&cur2[b], 1);
        pairs[p] = ((unsigned long long)(unsigned)d[i] << 32) | (unsigned)s[i];
    }
    __syncthreads();

    for (int i = t; i < BCH; i += 256) {
        unsigned long long pr = pairs[i];
        int dv = (int)(pr >> 32);
        int b = dv >> 11;
        int excl = sc[b] - h[b];
        bp[base[b] + (i - excl)] = ((unsigned)(dv & 2047) << 18) | (unsigned)(pr & 0x3ffffu);
    }
}

// Pass B: per-bucket node-hist (LDS) + scan + scatter
__global__ __launch_bounds__(1024) void k_fill3(const int* __restrict__ gbcnt,
                                                const unsigned* __restrict__ bp,
                                                int* __restrict__ hist,
                                                int* __restrict__ off,
                                                int* __restrict__ elist) {
    __shared__ int lh[2048];
    __shared__ int lcur[2048];
    __shared__ int ts[1024];
    const int b = blockIdx.x;   // 117 blocks
    const int lo = b * BCAP;
    const int hi = gbcnt[b];
    const int nbase = b * 2048;

    lh[threadIdx.x] = 0;
    lh[threadIdx.x + 1024] = 0;
    __syncthreads();

    for (int i = lo + threadIdx.x; i < hi; i += 1024) {
        atomicAdd(&lh[bp[i] >> 18], 1);
    }
    __syncthreads();

    int a0 = lh[2 * threadIdx.x];
    int a1 = lh[2 * threadIdx.x + 1];
    ts[threadIdx.x] = a0 + a1;
    __syncthreads();
    for (int d = 1; d < 1024; d <<= 1) {
        int v = (threadIdx.x >= d) ? ts[threadIdx.x - d] : 0;
        __syncthreads();
        ts[threadIdx.x] += v;
        __syncthreads();
    }
    int excl = ts[threadIdx.x] - (a0 + a1);
    int o0 = lo + excl;
    int o1 = o0 + a0;
    lcur[2 * threadIdx.x]     = o0;
    lcur[2 * threadIdx.x + 1] = o1;
    hist[nbase + 2 * threadIdx.x]     = a0;
    hist[nbase + 2 * threadIdx.x + 1] = a1;
    off[nbase + 2 * threadIdx.x]      = o0;
    off[nbase + 2 * threadIdx.x + 1]  = o1;
    __syncthreads();

    for (int i = lo + threadIdx.x; i < hi; i += 1024) {
        unsigned pr = bp[i];
        int pos = atomicAdd(&lcur[pr >> 18], 1);
        elist[pos] = (int)(pr & 0x3ffffu);
    }
}

// ---------------- x (f32) -> xb (bf16) ----------------
__global__ __launch_bounds__(256) void k_xprep(const float* __restrict__ x,
                                               unsigned short* __restrict__ xb) {
    int i = blockIdx.x * 256 + threadIdx.x;
    float4 f0 = *reinterpret_cast<const float4*>(x + (size_t)i * 8);
    float4 f1 = *reinterpret_cast<const float4*>(x + (size_t)i * 8 + 4);
    uint4 u;
    u.x = f2bf(f0.x) | ((unsigned)f2bf(f0.y) << 16);
    u.y = f2bf(f0.z) | ((unsigned)f2bf(f0.w) << 16);
    u.z = f2bf(f1.x) | ((unsigned)f2bf(f1.y) << 16);
    u.w = f2bf(f1.z) | ((unsigned)f2bf(f1.w) << 16);
    *reinterpret_cast<uint4*>(xb + (size_t)i * 8) = u;
}

// agg[n] = sum of bf16 x rows over in-edges; unrolled x2 for MLP
__global__ __launch_bounds__(256) void k_gather(const unsigned short* __restrict__ xb,
                                                const int* __restrict__ off,
                                                const int* __restrict__ hist,
                                                const int* __restrict__ elist,
                                                unsigned short* __restrict__ aggb) {
    int t = blockIdx.x * 256 + threadIdx.x;   // N*8 threads
    int n = t >> 3;
    int j = (t & 7) * 8;
    int start = off[n];
    int deg   = hist[n];
    float a[8];
    #pragma unroll
    for (int c = 0; c < 8; ++c) a[c] = 0.f;
    int i = 0;
    for (; i + 2 <= deg; i += 2) {
        int s0 = elist[start + i];
        int s1 = elist[start + i + 1];
        uint4 u0 = *reinterpret_cast<const uint4*>(xb + (size_t)s0 * IN_C + j);
        uint4 u1 = *reinterpret_cast<const uint4*>(xb + (size_t)s1 * IN_C + j);
        unsigned w0[4] = {u0.x, u0.y, u0.z, u0.w};
        unsigned w1[4] = {u1.x, u1.y, u1.z, u1.w};
        #pragma unroll
        for (int c = 0; c < 4; ++c) {
            a[2 * c]     += __builtin_bit_cast(float, w0[c] << 16);
            a[2 * c + 1] += __builtin_bit_cast(float, w0[c] & 0xffff0000u);
            a[2 * c]     += __builtin_bit_cast(float, w1[c] << 16);
            a[2 * c + 1] += __builtin_bit_cast(float, w1[c] & 0xffff0000u);
        }
    }
    if (i < deg) {
        int s0 = elist[start + i];
        uint4 u0 = *reinterpret_cast<const uint4*>(xb + (size_t)s0 * IN_C + j);
        unsigned w0[4] = {u0.x, u0.y, u0.z, u0.w};
        #pragma unroll
        for (int c = 0; c < 4; ++c) {
            a[2 * c]     += __builtin_bit_cast(float, w0[c] << 16);
            a[2 * c + 1] += __builtin_bit_cast(float, w0[c] & 0xffff0000u);
        }
    }
    uint4 o;
    o.x = f2bf(a[0]) | ((unsigned)f2bf(a[1]) << 16);
    o.y = f2bf(a[2]) | ((unsigned)f2bf(a[3]) << 16);
    o.z = f2bf(a[4]) | ((unsigned)f2bf(a[5]) << 16);
    o.w = f2bf(a[6]) | ((unsigned)f2bf(a[7]) << 16);
    *reinterpret_cast<uint4*>(aggb + (size_t)n * IN_C + j) = o;
}

// --- pack Wcat -> bf16 B-fragments [4][8][64][8] ---
__global__ __launch_bounds__(256) void k_wprep2(const float* __restrict__ Wrel,
                                                const float* __restrict__ Wroot,
                                                unsigned short* __restrict__ wG) {
    int i = blockIdx.x * 256 + threadIdx.x;
    int j    = i & 7;
    int lane = (i >> 3) & 63;
    int g    = (i >> 9) & 7;
    int ks   = i >> 12;
    int o    = g * 16 + (lane & 15);
    int k    = ks * 32 + ((lane >> 4) << 3) + j;
    float v = (k < IN_C) ? Wrel[k * OUT_C + o] : Wroot[(k - IN_C) * OUT_C + o];
    wG[i] = f2bf(v);
}

// ======== h = [agg||x] @ Wcat + b_rel via bf16 MFMA -> hb, 8 waves, LDS-staged out ========
__global__ __launch_bounds__(512) void k_gemm1(const unsigned short* __restrict__ aggb,
                                               const unsigned short* __restrict__ xb,
                                               const unsigned short* __restrict__ wG,
                                               const float* __restrict__ brel,
                                               unsigned short* __restrict__ hb,
                                               float* __restrict__ sums) {
    __shared__ unsigned short tile[GM * 128];   // 32 KB, XOR-swizzled 16B slots
    __shared__ float red[2][OUT_C];
    const int n0 = blockIdx.x * GM;

    for (int i = threadIdx.x; i < 2 * OUT_C; i += 512) (&red[0][0])[i] = 0.f;

    for (int i = threadIdx.x; i < GM * 16; i += 512) {
        int t = i >> 4, s = i & 15;
        const unsigned short* src = (s < 8) ? (aggb + (size_t)(n0 + t) * IN_C + s * 8)
                                            : (xb   + (size_t)(n0 + t) * IN_C + (s - 8) * 8);
        uint4 u = *reinterpret_cast<const uint4*>(src);
        int byte = t * 256 + (((s ^ (t & 7)) & 15) << 4);
        *reinterpret_cast<uint4*>(reinterpret_cast<char*>(tile) + byte) = u;
    }
    __syncthreads();

    const int w    = threadIdx.x >> 6;    // wave 0..7 -> rows [16w, 16w+16)
    const int lane = threadIdx.x & 63;
    const int r16  = lane & 15;
    const int kg   = lane >> 4;

    f32x4 acc[8];
    #pragma unroll
    for (int g = 0; g < 8; ++g) acc[g] = (f32x4){0.f, 0.f, 0.f, 0.f};

    for (int ks = 0; ks < 4; ++ks) {
        const int t = w * 16 + r16;
        const int slot = ks * 4 + kg;
        const int byte = t * 256 + (((slot ^ (t & 7)) & 15) << 4);
        uint4 ua = *reinterpret_cast<const uint4*>(reinterpret_cast<const char*>(tile) + byte);
        bf16x8 a = __builtin_bit_cast(bf16x8, ua);
        #pragma unroll
        for (int g = 0; g < 8; ++g) {
            uint4 u = *reinterpret_cast<const uint4*>(wG + (((ks * 8 + g) * 64 + lane) << 3));
            bf16x8 b = __builtin_bit_cast(bf16x8, u);
            acc[g] = __builtin_amdgcn_mfma_f32_16x16x32_bf16(a, b, acc[g], 0, 0, 0);
        }
    }
    __syncthreads();   // tile reads done before overwrite

    // C -> LDS (swizzled bf16) + fused BN1 stats
    #pragma unroll
    for (int g = 0; g < 8; ++g) {
        const int col  = g * 16 + r16;
        const int slot = col >> 3;
        const float bias = brel[col];
        float s = 0.f, q = 0.f;
        #pragma unroll
        for (int reg = 0; reg < 4; ++reg) {
            const int rl = w * 16 + kg * 4 + reg;
            float v = acc[g][reg] + bias;
            s += v;
            q += v * v;
            int byte = rl * 256 + (((slot ^ (rl & 7)) & 15) << 4) + (col & 7) * 2;
            *reinterpret_cast<unsigned short*>(reinterpret_cast<char*>(tile) + byte) = f2bf(v);
        }
        atomicAdd(&red[0][col], s);
        atomicAdd(&red[1][col], q);
    }
    __syncthreads();

    // coalesced copy-out + stats flush
    for (int i = threadIdx.x; i < GM * 16; i += 512) {
        int t = i >> 4, u = i & 15;
        int byte = t * 256 + (((u ^ (t & 7)) & 15) << 4);
        uint4 v = *reinterpret_cast<const uint4*>(reinterpret_cast<const char*>(tile) + byte);
        *reinterpret_cast<uint4*>(hb + (size_t)(n0 + t) * OUT_C + u * 8) = v;
    }
    if (threadIdx.x < OUT_C) {
        float* sb = sums + (blockIdx.x & (NSUM - 1)) * 256;
        atomicAdd(&sb[threadIdx.x], red[0][threadIdx.x]);
        atomicAdd(&sb[128 + threadIdx.x], red[1][threadIdx.x]);
    }
}

// ---------------- BN scale/shift from 8-copy sums ----------------
__global__ void k_bnparams(const float* __restrict__ sums,
                           const float* __restrict__ g,
                           const float* __restrict__ b,
                           float* __restrict__ sc, float* __restrict__ sh) {
    int c = threadIdx.x;   // 128 threads
    float s = 0.f, q = 0.f;
    #pragma unroll
    for (int r = 0; r < NSUM; ++r) {
        s += sums[r * 256 + c];
        q += sums[r * 256 + 128 + c];
    }
    const float inv_n = 1.0f / (float)N_NODES;
    float mean = s * inv_n;
    float var  = q * inv_n - mean * mean;
    float sv = g[c] * rsqrtf(var + EPSV);
    sc[c] = sv;
    sh[c] = b[c] - mean * sv;
}

// ----- pack conv_w -> bf16 B-fragments [12][8][64][8] -----
__global__ __launch_bounds__(256) void k_wprep(const float* __restrict__ w,
                                               unsigned short* __restrict__ wBf) {
    int i = blockIdx.x * 256 + threadIdx.x;
    int j    = i & 7;
    int lane = (i >> 3) & 63;
    int g    = (i >> 9) & 7;
    int ks   = i >> 12;
    int o    = g * 16 + (lane & 15);
    int ci   = (ks & 3) * 32 + ((lane >> 4) << 3) + j;
    int ktap = ks >> 2;
    wBf[i] = f2bf(w[o * (OUT_C * KW) + ci * KW + ktap]);
}

// ----- pack res_w -> bf16 B-fragments [2][8][64][8] -----
__global__ __launch_bounds__(256) void k_wprep3(const float* __restrict__ rw,
                                                unsigned short* __restrict__ wR) {
    int i = blockIdx.x * 256 + threadIdx.x;
    int j    = i & 7;
    int lane = (i >> 3) & 63;
    int g    = (i >> 9) & 7;
    int ks   = i >> 12;
    int o    = g * 16 + (lane & 15);
    int k    = ks * 32 + ((lane >> 4) << 3) + j;
    wR[i] = f2bf(rw[o * IN_C + k]);
}

// ------- Conv1d via bf16 MFMA: 128-row tile, B-frag prefetch, 8-copy stats -------
__global__ __launch_bounds__(256) void k_conv(const unsigned short* __restrict__ hb,
                                              const unsigned short* __restrict__ wBf,
                                              const float* __restrict__ cbv,
                                              const float* __restrict__ sc,
                                              const float* __restrict__ sh,
                                              unsigned short* __restrict__ cbuf,
                                              float* __restrict__ sums) {
    __shared__ unsigned short tile[(LCH + 2) * OUT_C];   // 33.3 KB
    __shared__ float red[2][OUT_C];
    const int b  = blockIdx.x >> 2;
    const int ch = blockIdx.x & 3;
    const int l0 = ch * LCH;
    const unsigned short* hbp = hb + (size_t)b * NLM * OUT_C;

    for (int i = threadIdx.x; i < 2 * OUT_C; i += 256) (&red[0][0])[i] = 0.f;

    for (int i = threadIdx.x; i < (LCH + 2) * 16; i += 256) {
        int t = i >> 4;
        int s = i & 15;
        int l = l0 - 1 + t;
        uint4 u = make_uint4(0u, 0u, 0u, 0u);
        if (l >= 0 && l < NLM) {
            uint4 r = *reinterpret_cast<const uint4*>(hbp + (size_t)l * OUT_C + s * 8);
            unsigned wd[4] = {r.x, r.y, r.z, r.w};
            unsigned od[4];
            #pragma unroll
            for (int c2 = 0; c2 < 4; ++c2) {
                int c = s * 8 + c2 * 2;
                float lo = __builtin_bit_cast(float, wd[c2] << 16);
                float hi = __builtin_bit_cast(float, wd[c2] & 0xffff0000u);
                lo = fmaxf(0.f, lo * sc[c] + sh[c]);
                hi = fmaxf(0.f, hi * sc[c + 1] + sh[c + 1]);
                od[c2] = f2bf(lo) | ((unsigned)f2bf(hi) << 16);
            }
            u = make_uint4(od[0], od[1], od[2], od[3]);
        }
        int byte = t * 256 + (((s ^ (t & 7)) & 15) << 4);
        *reinterpret_cast<uint4*>(reinterpret_cast<char*>(tile) + byte) = u;
    }
    __syncthreads();

    const int w    = threadIdx.x >> 6;
    const int lane = threadIdx.x & 63;
    const int r16  = lane & 15;
    const int kg   = lane >> 4;

    f32x4 acc[8][2];
    #pragma unroll
    for (int rs = 0; rs < 8; ++rs)
        #pragma unroll
        for (int cs = 0; cs < 2; ++cs)
            acc[rs][cs] = (f32x4){0.f, 0.f, 0.f, 0.f};

    uint4 ucur0 = *reinterpret_cast<const uint4*>(wBf + (((0 * 8 + w * 2 + 0) * 64 + lane) << 3));
    uint4 ucur1 = *reinterpret_cast<const uint4*>(wBf + (((0 * 8 + w * 2 + 1) * 64 + lane) << 3));
    for (int ks = 0; ks < 12; ++ks) {
        uint4 unx0, unx1;
        if (ks < 11) {
            unx0 = *reinterpret_cast<const uint4*>(wBf + ((((ks + 1) * 8 + w * 2 + 0) * 64 + lane) << 3));
            unx1 = *reinterpret_cast<const uint4*>(wBf + ((((ks + 1) * 8 + w * 2 + 1) * 64 + lane) << 3));
        }
        bf16x8 b0 = __builtin_bit_cast(bf16x8, ucur0);
        bf16x8 b1 = __builtin_bit_cast(bf16x8, ucur1);
        const int ktap = ks >> 2;
        const int slotbase = (ks & 3) * 4 + kg;
        #pragma unroll
        for (int rs = 0; rs < 8; ++rs) {
            const int t = rs * 16 + r16 + ktap;
            const int byte = t * 256 + (((slotbase ^ (t & 7)) & 15) << 4);
            uint4 u = *reinterpret_cast<const uint4*>(reinterpret_cast<const char*>(tile) + byte);
            bf16x8 af = __builtin_bit_cast(bf16x8, u);
            acc[rs][0] = __builtin_amdgcn_mfma_f32_16x16x32_bf16(af, b0, acc[rs][0], 0, 0, 0);
            acc[rs][1] = __builtin_amdgcn_mfma_f32_16x16x32_bf16(af, b1, acc[rs][1], 0, 0, 0);
        }
        ucur0 = unx0;
        ucur1 = unx1;
    }

    #pragma unroll
    for (int cs = 0; cs < 2; ++cs) {
        const int col = w * 32 + cs * 16 + r16;
        const float bias = cbv[col];
        float s = 0.f, q = 0.f;
        #pragma unroll
        for (int rs = 0; rs < 8; ++rs) {
            #pragma unroll
            for (int reg = 0; reg < 4; ++reg) {
                int l = l0 + rs * 16 + kg * 4 + reg;
                if (l < NLM) {
                    float v = acc[rs][cs][reg] + bias;
                    cbuf[((size_t)b * NLM + l) * OUT_C + col] = f2bf(v);
                    s += v;
                    q += v * v;
                }
            }
        }
        atomicAdd(&red[0][col], s);
        atomicAdd(&red[1][col], q);
    }
    __syncthreads();
    if (threadIdx.x < OUT_C) {
        float* sb = sums + (blockIdx.x & (NSUM - 1)) * 256;
        atomicAdd(&sb[threadIdx.x], red[0][threadIdx.x]);
        atomicAdd(&sb[128 + threadIdx.x], red[1][threadIdx.x]);
    }
}

// ---- final: residual = xb @ wR via MFMA; out = BN2+ReLU(cbuf) + residual + rb ----
__global__ __launch_bounds__(256) void k_final(const unsigned short* __restrict__ cbuf,
                                               const unsigned short* __restrict__ xb,
                                               const unsigned short* __restrict__ wR,
                                               const float* __restrict__ rb,
                                               const float* __restrict__ sc,
                                               const float* __restrict__ sh,
                                               float* __restrict__ out) {
    __shared__ unsigned short tile[GM * IN_C];
    const int n0 = blockIdx.x * GM;

    for (int i = threadIdx.x; i < GM * 8; i += 256) {
        int t = i >> 3, s = i & 7;
        uint4 u = *reinterpret_cast<const uint4*>(xb + (size_t)(n0 + t) * IN_C + s * 8);
        int byte = t * 128 + (((s ^ (t & 7)) & 7) << 4);
        *reinterpret_cast<uint4*>(reinterpret_cast<char*>(tile) + byte) = u;
    }
    __syncthreads();

    const int w    = threadIdx.x >> 6;
    const int lane = threadIdx.x & 63;
    const int r16  = lane & 15;
    const int kg   = lane >> 4;

    f32x4 acc[2][8];
    #pragma unroll
    for (int rs = 0; rs < 2; ++rs)
        #pragma unroll
        for (int g = 0; g < 8; ++g)
            acc[rs][g] = (f32x4){0.f, 0.f, 0.f, 0.f};

    #pragma unroll
    for (int ks = 0; ks < 2; ++ks) {
        bf16x8 a[2];
        #pragma unroll
        for (int rs = 0; rs < 2; ++rs) {
            const int t = w * 32 + rs * 16 + r16;
            const int slot = ks * 4 + kg;
            const int byte = t * 128 + (((slot ^ (t & 7)) & 7) << 4);
            uint4 u = *reinterpret_cast<const uint4*>(reinterpret_cast<const char*>(tile) + byte);
            a[rs] = __builtin_bit_cast(bf16x8, u);
        }
        #pragma unroll
        for (int g = 0; g < 8; ++g) {
            uint4 u = *reinterpret_cast<const uint4*>(wR + (((ks * 8 + g) * 64 + lane) << 3));
            bf16x8 b = __builtin_bit_cast(bf16x8, u);
            acc[0][g] = __builtin_amdgcn_mfma_f32_16x16x32_bf16(a[0], b, acc[0][g], 0, 0, 0);
            acc[1][g] = __builtin_amdgcn_mfma_f32_16x16x32_bf16(a[1], b, acc[1][g], 0, 0, 0);
        }
    }

    #pragma unroll
    for (int g = 0; g < 8; ++g) {
        const int col = g * 16 + r16;
        const float bias = rb[col];
        const float scv = sc[col];
        const float shv = sh[col];
        #pragma unroll
        for (int rs = 0; rs < 2; ++rs) {
            #pragma unroll
            for (int reg = 0; reg < 4; ++reg) {
                const size_t row = (size_t)(n0 + w * 32 + rs * 16 + kg * 4 + reg);
                float cv = bf2f(cbuf[row * OUT_C + col]);
                out[row * OUT_C + col] = fmaxf(0.f, cv * scv + shv) + acc[rs][g][reg] + bias;
            }
        }
    }
}

extern "C" void kernel_launch(void* const* d_in, const int* in_sizes, int n_in,
                              void* d_out, int out_size, void* d_ws, size_t ws_size,
                              hipStream_t stream) {
    const float* x     = (const float*)d_in[0];
    const int*   ei    = (const int*)d_in[1];
    const float* Wrel  = (const float*)d_in[3];
    const float* brel  = (const float*)d_in[4];
    const float* Wroot = (const float*)d_in[5];
    const float* bn1g  = (const float*)d_in[6];
    const float* bn1b  = (const float*)d_in[7];
    const float* convw = (const float*)d_in[8];
    const float* convb = (const float*)d_in[9];
    const float* bn2g  = (const float*)d_in[10];
    const float* bn2b  = (const float*)d_in[11];
    const float* resw  = (const float*)d_in[12];
    const float* resb  = (const float*)d_in[13];
    float* out = (float*)d_out;

    unsigned short* aggb = (unsigned short*)d_ws;             // N*64 bf16
    unsigned short* xb   = aggb + (size_t)N_NODES * IN_C;     // N*64 bf16
    unsigned short* hb   = xb + (size_t)N_NODES * IN_C;       // N*128 bf16
    unsigned short* cbuf = hb + (size_t)N_NODES * OUT_C;      // N*128 bf16
    float* st = (float*)(cbuf + (size_t)N_NODES * OUT_C);
    float* sums1 = st;               // 8 copies x 256
    float* sums2 = st + 2048;        // 8 copies x 256
    float* sc1 = st + 4096; float* sh1 = st + 4224;
    float* sc2 = st + 4352; float* sh2 = st + 4480;
    unsigned short* wBf = (unsigned short*)(st + 4608);       // 49152 bf16
    unsigned short* wG  = wBf + 49152;                        // 16384 bf16
    unsigned short* wR  = wG + 16384;                         // 8192 bf16

    // CSR + bucket arrays inside hb's memory (hb written only after gather):
    // hist(N) off(N) gbcnt(128) elist(117*BCAP) bp(117*BCAP u32) = ~36.5 MB < 61.3 MB
    int* hist   = (int*)hb;
    int* off    = hist + N_NODES;
    int* gbcnt  = off + N_NODES;
    int* elist  = gbcnt + 128;
    unsigned* bp = (unsigned*)(elist + NBUCK * BCAP);

    hipMemsetAsync(st, 0, 4096 * sizeof(float), stream);

    k_xprep <<<N_NODES / 32, 256, 0, stream>>>(x, xb);
    k_wprep <<<192, 256, 0, stream>>>(convw, wBf);
    k_wprep2<<<64, 256, 0, stream>>>(Wrel, Wroot, wG);
    k_wprep3<<<32, 256, 0, stream>>>(resw, wR);
    k_binit <<<1, 128, 0, stream>>>(gbcnt);
    k_bucket<<<NEDGE / BCH, 256, 0, stream>>>(ei, gbcnt, bp);
    k_fill3 <<<NBUCK, 1024, 0, stream>>>(gbcnt, bp, hist, off, elist);
    k_gather<<<(N_NODES * 8) / 256, 256, 0, stream>>>(xb, off, hist, elist, aggb);

    k_gemm1<<<N_NODES / GM, 512, 0, stream>>>(aggb, xb, wG, brel, hb, sums1);
    k_bnparams<<<1, 128, 0, stream>>>(sums1, bn1g, bn1b, sc1, sh1);
    k_conv<<<BSZ * NCHK, 256, 0, stream>>>(hb, wBf, convb, sc1, sh1, cbuf, sums2);
    k_bnparams<<<1, 128, 0, stream>>>(sums2, bn2g, bn2b, sc2, sh2);
    k_final<<<N_NODES / GM, 256, 0, stream>>>(cbuf, xb, wR, resb, sc2, sh2, out);
}

// Round 18
// 357.138 us; speedup vs baseline: 1.1000x; 1.1000x over previous
//
#include <hip/hip_runtime.h>

#define N_NODES 239616
#define NLM 468
#define BSZ 512
#define NEDGE 3833856
#define IN_C 64
#define OUT_C 128
#define KW 3
#define EPSV 1e-5f

#define GM 128      // nodes per gemm1/final block (MFMA tile M)
#define LCH 128     // L-rows per conv block
#define NCHK 4
#define NBUCK 117   // dst>>11 buckets (2048 nodes each; 117*2048 == N exactly)
#define BCH 4096    // edges per k_bucket block (E = 4096*936 exactly)
#define BCAP 36864  // fixed bucket capacity (mean 32768 + 22 sigma)
#define NSUM 8      // replicated stats buffers

typedef __attribute__((ext_vector_type(8))) __bf16 bf16x8;
typedef __attribute__((ext_vector_type(4))) float f32x4;

__device__ inline unsigned short f2bf(float f) {
    unsigned int u = __builtin_bit_cast(unsigned int, f);
    u = (u + 0x7FFFu + ((u >> 16) & 1u)) >> 16;
    return (unsigned short)u;
}
__device__ inline float bf2f(unsigned short b) {
    return __builtin_bit_cast(float, (unsigned)b << 16);
}

// ================= CSR build (bucketed counting sort by dst) =================

__global__ void k_binit(int* __restrict__ gbcnt) {
    int b = threadIdx.x;
    if (b < NBUCK) gbcnt[b] = b * BCAP;
}

// Pass A: block-local radix scatter; bp holds u32-packed (local_dst<<18 | src)
__global__ __launch_bounds__(256) void k_bucket(const int* __restrict__ ei,
                                                int* __restrict__ gbcnt,
                                                unsigned* __restrict__ bp) {
    __shared__ int h[128], sc[128], cur2[128], base[128];
    __shared__ unsigned long long pairs[BCH];   // 32 KB
    const int t = threadIdx.x;
    const int e0 = blockIdx.x * BCH;

    if (t < 128) h[t] = 0;
    __syncthreads();

    int d[16], s[16];
    #pragma unroll
    for (int i = 0; i < 16; ++i) {
        int e = e0 + i * 256 + t;
        d[i] = ei[NEDGE + e];
        s[i] = ei[e];
    }
    #pragma unroll
    for (int i = 0; i < 16; ++i) atomicAdd(&h[d[i] >> 11], 1);
    __syncthreads();

    if (t < 128) sc[t] = h[t];
    __syncthreads();
    for (int dd = 1; dd < 128; dd <<= 1) {
        int v = 0;
        if (t < 128 && t >= dd) v = sc[t - dd];
        __syncthreads();
        if (t < 128) sc[t] += v;
        __syncthreads();
    }
    if (t < 128) {
        int excl = sc[t] - h[t];
        cur2[t] = excl;
        base[t] = (h[t] > 0) ? atomicAdd(&gbcnt[t], h[t]) : 0;
    }
    __syncthreads();

    #pragma unroll
    for (int i = 0; i < 16; ++i) {
        int b = d[i] >> 11;
        int p = atomicAdd(&cur2[b], 1);
        pairs[p] = ((unsigned long long)(unsigned)d[i] << 32) | (unsigned)s[i];
    }
    __syncthreads();

    for (int i = t; i < BCH; i += 256) {
        unsigned long long pr = pairs[i];
        int dv = (int)(pr >> 32);
        int b = dv >> 11;
        int excl = sc[b] - h[b];
        bp[base[b] + (i - excl)] = ((unsigned)(dv & 2047) << 18) | (unsigned)(pr & 0x3ffffu);
    }
}

// Pass B: per-bucket node-hist (LDS) + scan + scatter
__global__ __launch_bounds__(1024) void k_fill3(const int* __restrict__ gbcnt,
                                                const unsigned* __restrict__ bp,
                                                int* __restrict__ hist,
                                                int* __restrict__ off,
                                                int* __restrict__ elist) {
    __shared__ int lh[2048];
    __shared__ int lcur[2048];
    __shared__ int ts[1024];
    const int b = blockIdx.x;   // 117 blocks
    const int lo = b * BCAP;
    const int hi = gbcnt[b];
    const int nbase = b * 2048;

    lh[threadIdx.x] = 0;
    lh[threadIdx.x + 1024] = 0;
    __syncthreads();

    for (int i = lo + threadIdx.x; i < hi; i += 1024) {
        atomicAdd(&lh[bp[i] >> 18], 1);
    }
    __syncthreads();

    int a0 = lh[2 * threadIdx.x];
    int a1 = lh[2 * threadIdx.x + 1];
    ts[threadIdx.x] = a0 + a1;
    __syncthreads();
    for (int d = 1; d < 1024; d <<= 1) {
        int v = (threadIdx.x >= d) ? ts[threadIdx.x - d] : 0;
        __syncthreads();
        ts[threadIdx.x] += v;
        __syncthreads();
    }
    int excl = ts[threadIdx.x] - (a0 + a1);
    int o0 = lo + excl;
    int o1 = o0 + a0;
    lcur[2 * threadIdx.x]     = o0;
    lcur[2 * threadIdx.x + 1] = o1;
    hist[nbase + 2 * threadIdx.x]     = a0;
    hist[nbase + 2 * threadIdx.x + 1] = a1;
    off[nbase + 2 * threadIdx.x]      = o0;
    off[nbase + 2 * threadIdx.x + 1]  = o1;
    __syncthreads();

    for (int i = lo + threadIdx.x; i < hi; i += 1024) {
        unsigned pr = bp[i];
        int pos = atomicAdd(&lcur[pr >> 18], 1);
        elist[pos] = (int)(pr & 0x3ffffu);
    }
}

// ---------------- x (f32) -> xb (bf16) ----------------
__global__ __launch_bounds__(256) void k_xprep(const float* __restrict__ x,
                                               unsigned short* __restrict__ xb) {
    int i = blockIdx.x * 256 + threadIdx.x;
    float4 f0 = *reinterpret_cast<const float4*>(x + (size_t)i * 8);
    float4 f1 = *reinterpret_cast<const float4*>(x + (size_t)i * 8 + 4);
    uint4 u;
    u.x = f2bf(f0.x) | ((unsigned)f2bf(f0.y) << 16);
    u.y = f2bf(f0.z) | ((unsigned)f2bf(f0.w) << 16);
    u.z = f2bf(f1.x) | ((unsigned)f2bf(f1.y) << 16);
    u.w = f2bf(f1.z) | ((unsigned)f2bf(f1.w) << 16);
    *reinterpret_cast<uint4*>(xb + (size_t)i * 8) = u;
}

// agg[n] = sum of bf16 x rows over in-edges; unrolled x2 for MLP
__global__ __launch_bounds__(256) void k_gather(const unsigned short* __restrict__ xb,
                                                const int* __restrict__ off,
                                                const int* __restrict__ hist,
                                                const int* __restrict__ elist,
                                                unsigned short* __restrict__ aggb) {
    int t = blockIdx.x * 256 + threadIdx.x;   // N*8 threads
    int n = t >> 3;
    int j = (t & 7) * 8;
    int start = off[n];
    int deg   = hist[n];
    float a[8];
    #pragma unroll
    for (int c = 0; c < 8; ++c) a[c] = 0.f;
    int i = 0;
    for (; i + 2 <= deg; i += 2) {
        int s0 = elist[start + i];
        int s1 = elist[start + i + 1];
        uint4 u0 = *reinterpret_cast<const uint4*>(xb + (size_t)s0 * IN_C + j);
        uint4 u1 = *reinterpret_cast<const uint4*>(xb + (size_t)s1 * IN_C + j);
        unsigned w0[4] = {u0.x, u0.y, u0.z, u0.w};
        unsigned w1[4] = {u1.x, u1.y, u1.z, u1.w};
        #pragma unroll
        for (int c = 0; c < 4; ++c) {
            a[2 * c]     += __builtin_bit_cast(float, w0[c] << 16);
            a[2 * c + 1] += __builtin_bit_cast(float, w0[c] & 0xffff0000u);
            a[2 * c]     += __builtin_bit_cast(float, w1[c] << 16);
            a[2 * c + 1] += __builtin_bit_cast(float, w1[c] & 0xffff0000u);
        }
    }
    if (i < deg) {
        int s0 = elist[start + i];
        uint4 u0 = *reinterpret_cast<const uint4*>(xb + (size_t)s0 * IN_C + j);
        unsigned w0[4] = {u0.x, u0.y, u0.z, u0.w};
        #pragma unroll
        for (int c = 0; c < 4; ++c) {
            a[2 * c]     += __builtin_bit_cast(float, w0[c] << 16);
            a[2 * c + 1] += __builtin_bit_cast(float, w0[c] & 0xffff0000u);
        }
    }
    uint4 o;
    o.x = f2bf(a[0]) | ((unsigned)f2bf(a[1]) << 16);
    o.y = f2bf(a[2]) | ((unsigned)f2bf(a[3]) << 16);
    o.z = f2bf(a[4]) | ((unsigned)f2bf(a[5]) << 16);
    o.w = f2bf(a[6]) | ((unsigned)f2bf(a[7]) << 16);
    *reinterpret_cast<uint4*>(aggb + (size_t)n * IN_C + j) = o;
}

// --- pack Wcat -> bf16 B-fragments [4][8][64][8] ---
__global__ __launch_bounds__(256) void k_wprep2(const float* __restrict__ Wrel,
                                                const float* __restrict__ Wroot,
                                                unsigned short* __restrict__ wG) {
    int i = blockIdx.x * 256 + threadIdx.x;
    int j    = i & 7;
    int lane = (i >> 3) & 63;
    int g    = (i >> 9) & 7;
    int ks   = i >> 12;
    int o    = g * 16 + (lane & 15);
    int k    = ks * 32 + ((lane >> 4) << 3) + j;
    float v = (k < IN_C) ? Wrel[k * OUT_C + o] : Wroot[(k - IN_C) * OUT_C + o];
    wG[i] = f2bf(v);
}

// ======== h = [agg||x] @ Wcat + b_rel via bf16 MFMA -> hb (bf16), fused BN1 stats ========
// A-fragments loaded DIRECTLY from global (no LDS tile, no staging barriers).
__global__ __launch_bounds__(256) void k_gemm1(const unsigned short* __restrict__ aggb,
                                               const unsigned short* __restrict__ xb,
                                               const unsigned short* __restrict__ wG,
                                               const float* __restrict__ brel,
                                               unsigned short* __restrict__ hb,
                                               float* __restrict__ sums) {
    __shared__ float red[2][OUT_C];
    const int n0 = blockIdx.x * GM;

    for (int i = threadIdx.x; i < 2 * OUT_C; i += 256) (&red[0][0])[i] = 0.f;
    __syncthreads();

    const int w    = threadIdx.x >> 6;    // wave -> rows [32w, 32w+32)
    const int lane = threadIdx.x & 63;
    const int r16  = lane & 15;
    const int kg   = lane >> 4;           // 0..3

    f32x4 acc[2][8];
    #pragma unroll
    for (int rs = 0; rs < 2; ++rs)
        #pragma unroll
        for (int g = 0; g < 8; ++g)
            acc[rs][g] = (f32x4){0.f, 0.f, 0.f, 0.f};

    // load all 8 A-fragments up front (independent 16B global loads)
    bf16x8 afr[4][2];
    #pragma unroll
    for (int ks = 0; ks < 4; ++ks) {
        #pragma unroll
        for (int rs = 0; rs < 2; ++rs) {
            const int row = n0 + w * 32 + rs * 16 + r16;
            const int k0 = ks * 32 + kg * 8;
            const unsigned short* src = (ks < 2) ? (aggb + (size_t)row * IN_C + k0)
                                                 : (xb   + (size_t)row * IN_C + (k0 - 64));
            uint4 u = *reinterpret_cast<const uint4*>(src);
            afr[ks][rs] = __builtin_bit_cast(bf16x8, u);
        }
    }

    #pragma unroll
    for (int ks = 0; ks < 4; ++ks) {
        #pragma unroll
        for (int g = 0; g < 8; ++g) {
            uint4 u = *reinterpret_cast<const uint4*>(wG + (((ks * 8 + g) * 64 + lane) << 3));
            bf16x8 b = __builtin_bit_cast(bf16x8, u);
            acc[0][g] = __builtin_amdgcn_mfma_f32_16x16x32_bf16(afr[ks][0], b, acc[0][g], 0, 0, 0);
            acc[1][g] = __builtin_amdgcn_mfma_f32_16x16x32_bf16(afr[ks][1], b, acc[1][g], 0, 0, 0);
        }
    }

    // epilogue: bias, store hb bf16, fused BN1 stats
    #pragma unroll
    for (int g = 0; g < 8; ++g) {
        const int col = g * 16 + r16;
        const float bias = brel[col];
        float s = 0.f, q = 0.f;
        #pragma unroll
        for (int rs = 0; rs < 2; ++rs) {
            #pragma unroll
            for (int reg = 0; reg < 4; ++reg) {
                const int row = n0 + w * 32 + rs * 16 + kg * 4 + reg;
                float v = acc[rs][g][reg] + bias;
                hb[(size_t)row * OUT_C + col] = f2bf(v);
                s += v;
                q += v * v;
            }
        }
        atomicAdd(&red[0][col], s);
        atomicAdd(&red[1][col], q);
    }
    __syncthreads();
    if (threadIdx.x < OUT_C) {
        float* sb = sums + (blockIdx.x & (NSUM - 1)) * 256;
        atomicAdd(&sb[threadIdx.x], red[0][threadIdx.x]);
        atomicAdd(&sb[128 + threadIdx.x], red[1][threadIdx.x]);
    }
}

// ---------------- BN scale/shift from 8-copy sums ----------------
__global__ void k_bnparams(const float* __restrict__ sums,
                           const float* __restrict__ g,
                           const float* __restrict__ b,
                           float* __restrict__ sc, float* __restrict__ sh) {
    int c = threadIdx.x;   // 128 threads
    float s = 0.f, q = 0.f;
    #pragma unroll
    for (int r = 0; r < NSUM; ++r) {
        s += sums[r * 256 + c];
        q += sums[r * 256 + 128 + c];
    }
    const float inv_n = 1.0f / (float)N_NODES;
    float mean = s * inv_n;
    float var  = q * inv_n - mean * mean;
    float sv = g[c] * rsqrtf(var + EPSV);
    sc[c] = sv;
    sh[c] = b[c] - mean * sv;
}

// ----- pack conv_w -> bf16 B-fragments [12][8][64][8] -----
__global__ __launch_bounds__(256) void k_wprep(const float* __restrict__ w,
                                               unsigned short* __restrict__ wBf) {
    int i = blockIdx.x * 256 + threadIdx.x;
    int j    = i & 7;
    int lane = (i >> 3) & 63;
    int g    = (i >> 9) & 7;
    int ks   = i >> 12;
    int o    = g * 16 + (lane & 15);
    int ci   = (ks & 3) * 32 + ((lane >> 4) << 3) + j;
    int ktap = ks >> 2;
    wBf[i] = f2bf(w[o * (OUT_C * KW) + ci * KW + ktap]);
}

// ----- pack res_w -> bf16 B-fragments [2][8][64][8] -----
__global__ __launch_bounds__(256) void k_wprep3(const float* __restrict__ rw,
                                                unsigned short* __restrict__ wR) {
    int i = blockIdx.x * 256 + threadIdx.x;
    int j    = i & 7;
    int lane = (i >> 3) & 63;
    int g    = (i >> 9) & 7;
    int ks   = i >> 12;
    int o    = g * 16 + (lane & 15);
    int k    = ks * 32 + ((lane >> 4) << 3) + j;
    wR[i] = f2bf(rw[o * IN_C + k]);
}

// ------- Conv1d via bf16 MFMA: 128-row tile, B-frag prefetch, 8-copy stats -------
__global__ __launch_bounds__(256) void k_conv(const unsigned short* __restrict__ hb,
                                              const unsigned short* __restrict__ wBf,
                                              const float* __restrict__ cbv,
                                              const float* __restrict__ sc,
                                              const float* __restrict__ sh,
                                              unsigned short* __restrict__ cbuf,
                                              float* __restrict__ sums) {
    __shared__ unsigned short tile[(LCH + 2) * OUT_C];   // 33.3 KB
    __shared__ float red[2][OUT_C];
    const int b  = blockIdx.x >> 2;
    const int ch = blockIdx.x & 3;
    const int l0 = ch * LCH;
    const unsigned short* hbp = hb + (size_t)b * NLM * OUT_C;

    for (int i = threadIdx.x; i < 2 * OUT_C; i += 256) (&red[0][0])[i] = 0.f;

    for (int i = threadIdx.x; i < (LCH + 2) * 16; i += 256) {
        int t = i >> 4;
        int s = i & 15;
        int l = l0 - 1 + t;
        uint4 u = make_uint4(0u, 0u, 0u, 0u);
        if (l >= 0 && l < NLM) {
            uint4 r = *reinterpret_cast<const uint4*>(hbp + (size_t)l * OUT_C + s * 8);
            unsigned wd[4] = {r.x, r.y, r.z, r.w};
            unsigned od[4];
            #pragma unroll
            for (int c2 = 0; c2 < 4; ++c2) {
                int c = s * 8 + c2 * 2;
                float lo = __builtin_bit_cast(float, wd[c2] << 16);
                float hi = __builtin_bit_cast(float, wd[c2] & 0xffff0000u);
                lo = fmaxf(0.f, lo * sc[c] + sh[c]);
                hi = fmaxf(0.f, hi * sc[c + 1] + sh[c + 1]);
                od[c2] = f2bf(lo) | ((unsigned)f2bf(hi) << 16);
            }
            u = make_uint4(od[0], od[1], od[2], od[3]);
        }
        int byte = t * 256 + (((s ^ (t & 7)) & 15) << 4);
        *reinterpret_cast<uint4*>(reinterpret_cast<char*>(tile) + byte) = u;
    }
    __syncthreads();

    const int w    = threadIdx.x >> 6;
    const int lane = threadIdx.x & 63;
    const int r16  = lane & 15;
    const int kg   = lane >> 4;

    f32x4 acc[8][2];
    #pragma unroll
    for (int rs = 0; rs < 8; ++rs)
        #pragma unroll
        for (int cs = 0; cs < 2; ++cs)
            acc[rs][cs] = (f32x4){0.f, 0.f, 0.f, 0.f};

    uint4 ucur0 = *reinterpret_cast<const uint4*>(wBf + (((0 * 8 + w * 2 + 0) * 64 + lane) << 3));
    uint4 ucur1 = *reinterpret_cast<const uint4*>(wBf + (((0 * 8 + w * 2 + 1) * 64 + lane) << 3));
    for (int ks = 0; ks < 12; ++ks) {
        uint4 unx0, unx1;
        if (ks < 11) {
            unx0 = *reinterpret_cast<const uint4*>(wBf + ((((ks + 1) * 8 + w * 2 + 0) * 64 + lane) << 3));
            unx1 = *reinterpret_cast<const uint4*>(wBf + ((((ks + 1) * 8 + w * 2 + 1) * 64 + lane) << 3));
        }
        bf16x8 b0 = __builtin_bit_cast(bf16x8, ucur0);
        bf16x8 b1 = __builtin_bit_cast(bf16x8, ucur1);
        const int ktap = ks >> 2;
        const int slotbase = (ks & 3) * 4 + kg;
        #pragma unroll
        for (int rs = 0; rs < 8; ++rs) {
            const int t = rs * 16 + r16 + ktap;
            const int byte = t * 256 + (((slotbase ^ (t & 7)) & 15) << 4);
            uint4 u = *reinterpret_cast<const uint4*>(reinterpret_cast<const char*>(tile) + byte);
            bf16x8 af = __builtin_bit_cast(bf16x8, u);
            acc[rs][0] = __builtin_amdgcn_mfma_f32_16x16x32_bf16(af, b0, acc[rs][0], 0, 0, 0);
            acc[rs][1] = __builtin_amdgcn_mfma_f32_16x16x32_bf16(af, b1, acc[rs][1], 0, 0, 0);
        }
        ucur0 = unx0;
        ucur1 = unx1;
    }

    #pragma unroll
    for (int cs = 0; cs < 2; ++cs) {
        const int col = w * 32 + cs * 16 + r16;
        const float bias = cbv[col];
        float s = 0.f, q = 0.f;
        #pragma unroll
        for (int rs = 0; rs < 8; ++rs) {
            #pragma unroll
            for (int reg = 0; reg < 4; ++reg) {
                int l = l0 + rs * 16 + kg * 4 + reg;
                if (l < NLM) {
                    float v = acc[rs][cs][reg] + bias;
                    cbuf[((size_t)b * NLM + l) * OUT_C + col] = f2bf(v);
                    s += v;
                    q += v * v;
                }
            }
        }
        atomicAdd(&red[0][col], s);
        atomicAdd(&red[1][col], q);
    }
    __syncthreads();
    if (threadIdx.x < OUT_C) {
        float* sb = sums + (blockIdx.x & (NSUM - 1)) * 256;
        atomicAdd(&sb[threadIdx.x], red[0][threadIdx.x]);
        atomicAdd(&sb[128 + threadIdx.x], red[1][threadIdx.x]);
    }
}

// ---- final: residual = xb @ wR via MFMA; out = BN2+ReLU(cbuf) + residual + rb ----
__global__ __launch_bounds__(256) void k_final(const unsigned short* __restrict__ cbuf,
                                               const unsigned short* __restrict__ xb,
                                               const unsigned short* __restrict__ wR,
                                               const float* __restrict__ rb,
                                               const float* __restrict__ sc,
                                               const float* __restrict__ sh,
                                               float* __restrict__ out) {
    __shared__ unsigned short tile[GM * IN_C];
    const int n0 = blockIdx.x * GM;

    for (int i = threadIdx.x; i < GM * 8; i += 256) {
        int t = i >> 3, s = i & 7;
        uint4 u = *reinterpret_cast<const uint4*>(xb + (size_t)(n0 + t) * IN_C + s * 8);
        int byte = t * 128 + (((s ^ (t & 7)) & 7) << 4);
        *reinterpret_cast<uint4*>(reinterpret_cast<char*>(tile) + byte) = u;
    }
    __syncthreads();

    const int w    = threadIdx.x >> 6;
    const int lane = threadIdx.x & 63;
    const int r16  = lane & 15;
    const int kg   = lane >> 4;

    f32x4 acc[2][8];
    #pragma unroll
    for (int rs = 0; rs < 2; ++rs)
        #pragma unroll
        for (int g = 0; g < 8; ++g)
            acc[rs][g] = (f32x4){0.f, 0.f, 0.f, 0.f};

    #pragma unroll
    for (int ks = 0; ks < 2; ++ks) {
        bf16x8 a[2];
        #pragma unroll
        for (int rs = 0; rs < 2; ++rs) {
            const int t = w * 32 + rs * 16 + r16;
            const int slot = ks * 4 + kg;
            const int byte = t * 128 + (((slot ^ (t & 7)) & 7) << 4);
            uint4 u = *reinterpret_cast<const uint4*>(reinterpret_cast<const char*>(tile) + byte);
            a[rs] = __builtin_bit_cast(bf16x8, u);
        }
        #pragma unroll
        for (int g = 0; g < 8; ++g) {
            uint4 u = *reinterpret_cast<const uint4*>(wR + (((ks * 8 + g) * 64 + lane) << 3));
            bf16x8 b = __builtin_bit_cast(bf16x8, u);
            acc[0][g] = __builtin_amdgcn_mfma_f32_16x16x32_bf16(a[0], b, acc[0][g], 0, 0, 0);
            acc[1][g] = __builtin_amdgcn_mfma_f32_16x16x32_bf16(a[1], b, acc[1][g], 0, 0, 0);
        }
    }

    #pragma unroll
    for (int g = 0; g < 8; ++g) {
        const int col = g * 16 + r16;
        const float bias = rb[col];
        const float scv = sc[col];
        const float shv = sh[col];
        #pragma unroll
        for (int rs = 0; rs < 2; ++rs) {
            #pragma unroll
            for (int reg = 0; reg < 4; ++reg) {
                const size_t row = (size_t)(n0 + w * 32 + rs * 16 + kg * 4 + reg);
                float cv = bf2f(cbuf[row * OUT_C + col]);
                out[row * OUT_C + col] = fmaxf(0.f, cv * scv + shv) + acc[rs][g][reg] + bias;
            }
        }
    }
}

extern "C" void kernel_launch(void* const* d_in, const int* in_sizes, int n_in,
                              void* d_out, int out_size, void* d_ws, size_t ws_size,
                              hipStream_t stream) {
    const float* x     = (const float*)d_in[0];
    const int*   ei    = (const int*)d_in[1];
    const float* Wrel  = (const float*)d_in[3];
    const float* brel  = (const float*)d_in[4];
    const float* Wroot = (const float*)d_in[5];
    const float* bn1g  = (const float*)d_in[6];
    const float* bn1b  = (const float*)d_in[7];
    const float* convw = (const float*)d_in[8];
    const float* convb = (const float*)d_in[9];
    const float* bn2g  = (const float*)d_in[10];
    const float* bn2b  = (const float*)d_in[11];
    const float* resw  = (const float*)d_in[12];
    const float* resb  = (const float*)d_in[13];
    float* out = (float*)d_out;

    unsigned short* aggb = (unsigned short*)d_ws;             // N*64 bf16
    unsigned short* xb   = aggb + (size_t)N_NODES * IN_C;     // N*64 bf16
    unsigned short* hb   = xb + (size_t)N_NODES * IN_C;       // N*128 bf16
    unsigned short* cbuf = hb + (size_t)N_NODES * OUT_C;      // N*128 bf16
    float* st = (float*)(cbuf + (size_t)N_NODES * OUT_C);
    float* sums1 = st;               // 8 copies x 256
    float* sums2 = st + 2048;        // 8 copies x 256
    float* sc1 = st + 4096; float* sh1 = st + 4224;
    float* sc2 = st + 4352; float* sh2 = st + 4480;
    unsigned short* wBf = (unsigned short*)(st + 4608);       // 49152 bf16
    unsigned short* wG  = wBf + 49152;                        // 16384 bf16
    unsigned short* wR  = wG + 16384;                         // 8192 bf16

    // CSR + bucket arrays inside hb's memory (hb written only after gather):
    int* hist   = (int*)hb;
    int* off    = hist + N_NODES;
    int* gbcnt  = off + N_NODES;
    int* elist  = gbcnt + 128;
    unsigned* bp = (unsigned*)(elist + NBUCK * BCAP);

    hipMemsetAsync(st, 0, 4096 * sizeof(float), stream);

    k_xprep <<<N_NODES / 32, 256, 0, stream>>>(x, xb);
    k_wprep <<<192, 256, 0, stream>>>(convw, wBf);
    k_wprep2<<<64, 256, 0, stream>>>(Wrel, Wroot, wG);
    k_wprep3<<<32, 256, 0, stream>>>(resw, wR);
    k_binit <<<1, 128, 0, stream>>>(gbcnt);
    k_bucket<<<NEDGE / BCH, 256, 0, stream>>>(ei, gbcnt, bp);
    k_fill3 <<<NBUCK, 1024, 0, stream>>>(gbcnt, bp, hist, off, elist);
    k_gather<<<(N_NODES * 8) / 256, 256, 0, stream>>>(xb, off, hist, elist, aggb);

    k_gemm1<<<N_NODES / GM, 256, 0, stream>>>(aggb, xb, wG, brel, hb, sums1);
    k_bnparams<<<1, 128, 0, stream>>>(sums1, bn1g, bn1b, sc1, sh1);
    k_conv<<<BSZ * NCHK, 256, 0, stream>>>(hb, wBf, convb, sc1, sh1, cbuf, sums2);
    k_bnparams<<<1, 128, 0, stream>>>(sums2, bn2g, bn2b, sc2, sh2);
    k_final<<<N_NODES / GM, 256, 0, stream>>>(cbuf, xb, wR, resb, sc2, sh2, out);
}